// Round 2
// baseline (362.217 us; speedup 1.0000x reference)
//
#include <hip/hip_runtime.h>
#include <hip/hip_bf16.h>

typedef __attribute__((ext_vector_type(8))) short bf16x8;
typedef __attribute__((ext_vector_type(4))) float f32x4;

#define NH 12
#define HD 64
#define TT 1536
#define CC 768
#define BB 4
#define MM (BB * TT)   // 6144 rows

__device__ __forceinline__ unsigned short f2bf(float f) {
    unsigned int u = __builtin_bit_cast(unsigned int, f);
    return (unsigned short)((u + 0x7FFFu + ((u >> 16) & 1u)) >> 16);  // RNE
}

__global__ __launch_bounds__(256) void convert_k(const float* __restrict__ in,
                                                 unsigned short* __restrict__ out,
                                                 int n4) {
    int i = blockIdx.x * 256 + threadIdx.x;
    if (i >= n4) return;
    float4 v = reinterpret_cast<const float4*>(in)[i];
    ushort4 o = { f2bf(v.x), f2bf(v.y), f2bf(v.z), f2bf(v.w) };
    reinterpret_cast<ushort4*>(out)[i] = o;
}

// ---------------------------------------------------------------------------
// QKV projection GEMM: C[m,n] = sum_k A[m,k] * W[n,k]  (both K-contiguous)
// tile 128x128, 4 waves (each 64x64), BK=32, 16x16x32 bf16 MFMA.
// Epilogue: q -> [B,H,T,D] scaled 0.125; k -> [B,H,T,D]; v -> [B,H,D,T] (transposed!)
// ---------------------------------------------------------------------------
__global__ __launch_bounds__(256) void gemm_qkv(
    const unsigned short* __restrict__ xb,
    const unsigned short* __restrict__ wq, const float* __restrict__ bq,
    const unsigned short* __restrict__ wk, const float* __restrict__ bk,
    const unsigned short* __restrict__ wv, const float* __restrict__ bv,
    unsigned short* __restrict__ qo, unsigned short* __restrict__ ko,
    unsigned short* __restrict__ vo) {
    __shared__ unsigned short As[128][40];   // stride 80B: 2-way max on ds ops
    __shared__ unsigned short Bs[128][40];

    const int z = blockIdx.z;
    const unsigned short* W = (z == 0) ? wq : (z == 1) ? wk : wv;
    const float* bias = (z == 0) ? bq : (z == 1) ? bk : bv;
    unsigned short* out = (z == 0) ? qo : (z == 1) ? ko : vo;
    const float scale = (z == 0) ? 0.125f : 1.0f;

    const int m0 = blockIdx.y * 128;
    const int n0 = blockIdx.x * 128;
    const int tid = threadIdx.x;
    const int lane = tid & 63;
    const int w = tid >> 6;
    const int wr = w >> 1, wc = w & 1;
    const int fr = lane & 15, fg = lane >> 4;

    f32x4 acc[4][4];
#pragma unroll
    for (int i = 0; i < 4; i++)
#pragma unroll
        for (int j = 0; j < 4; j++) acc[i][j] = (f32x4){0.f, 0.f, 0.f, 0.f};

    for (int k0 = 0; k0 < CC; k0 += 32) {
        __syncthreads();
        for (int c = tid; c < 512; c += 256) {     // 128 rows x 4 colgroups of 8
            int row = c >> 2, cg = c & 3;
            *reinterpret_cast<uint4*>(&As[row][cg * 8]) =
                *reinterpret_cast<const uint4*>(&xb[(size_t)(m0 + row) * CC + k0 + cg * 8]);
            *reinterpret_cast<uint4*>(&Bs[row][cg * 8]) =
                *reinterpret_cast<const uint4*>(&W[(size_t)(n0 + row) * CC + k0 + cg * 8]);
        }
        __syncthreads();
        bf16x8 a[4], b[4];
#pragma unroll
        for (int mi = 0; mi < 4; mi++)
            a[mi] = *reinterpret_cast<const bf16x8*>(&As[wr * 64 + mi * 16 + fr][fg * 8]);
#pragma unroll
        for (int ni = 0; ni < 4; ni++)
            b[ni] = *reinterpret_cast<const bf16x8*>(&Bs[wc * 64 + ni * 16 + fr][fg * 8]);
#pragma unroll
        for (int mi = 0; mi < 4; mi++)
#pragma unroll
            for (int ni = 0; ni < 4; ni++)
                acc[mi][ni] = __builtin_amdgcn_mfma_f32_16x16x32_bf16(
                    a[mi], b[ni], acc[mi][ni], 0, 0, 0);
    }

#pragma unroll
    for (int mi = 0; mi < 4; mi++)
#pragma unroll
        for (int ni = 0; ni < 4; ni++) {
            int n = n0 + wc * 64 + ni * 16 + fr;
            int h = n >> 6, d = n & 63;
            float bv_ = bias[n];
            int m_base = m0 + wr * 64 + mi * 16 + fg * 4;
            int b_ = m_base / TT, t0 = m_base % TT;   // 4 consecutive t in one b_
            if (z == 2) {
                // V transposed: [B,H,D,T], 4 consecutive t -> one 8B store
                size_t off = ((size_t)(b_ * NH + h) * HD + d) * (size_t)TT + t0;
                ushort4 o = { f2bf(acc[mi][ni][0] + bv_), f2bf(acc[mi][ni][1] + bv_),
                              f2bf(acc[mi][ni][2] + bv_), f2bf(acc[mi][ni][3] + bv_) };
                *reinterpret_cast<ushort4*>(&out[off]) = o;
            } else {
#pragma unroll
                for (int r = 0; r < 4; r++) {
                    size_t off = ((size_t)(b_ * NH + h) * TT + t0 + r) * (size_t)HD + d;
                    out[off] = f2bf((acc[mi][ni][r] + bv_) * scale);
                }
            }
        }
}

// ---------------------------------------------------------------------------
// Output projection GEMM: same structure, fp32 output [M, C] = d_out.
// ---------------------------------------------------------------------------
__global__ __launch_bounds__(256) void gemm_proj(
    const unsigned short* __restrict__ yb,
    const unsigned short* __restrict__ wp, const float* __restrict__ bp,
    float* __restrict__ out) {
    __shared__ unsigned short As[128][40];
    __shared__ unsigned short Bs[128][40];

    const int m0 = blockIdx.y * 128;
    const int n0 = blockIdx.x * 128;
    const int tid = threadIdx.x;
    const int lane = tid & 63;
    const int w = tid >> 6;
    const int wr = w >> 1, wc = w & 1;
    const int fr = lane & 15, fg = lane >> 4;

    f32x4 acc[4][4];
#pragma unroll
    for (int i = 0; i < 4; i++)
#pragma unroll
        for (int j = 0; j < 4; j++) acc[i][j] = (f32x4){0.f, 0.f, 0.f, 0.f};

    for (int k0 = 0; k0 < CC; k0 += 32) {
        __syncthreads();
        for (int c = tid; c < 512; c += 256) {
            int row = c >> 2, cg = c & 3;
            *reinterpret_cast<uint4*>(&As[row][cg * 8]) =
                *reinterpret_cast<const uint4*>(&yb[(size_t)(m0 + row) * CC + k0 + cg * 8]);
            *reinterpret_cast<uint4*>(&Bs[row][cg * 8]) =
                *reinterpret_cast<const uint4*>(&wp[(size_t)(n0 + row) * CC + k0 + cg * 8]);
        }
        __syncthreads();
        bf16x8 a[4], b[4];
#pragma unroll
        for (int mi = 0; mi < 4; mi++)
            a[mi] = *reinterpret_cast<const bf16x8*>(&As[wr * 64 + mi * 16 + fr][fg * 8]);
#pragma unroll
        for (int ni = 0; ni < 4; ni++)
            b[ni] = *reinterpret_cast<const bf16x8*>(&Bs[wc * 64 + ni * 16 + fr][fg * 8]);
#pragma unroll
        for (int mi = 0; mi < 4; mi++)
#pragma unroll
            for (int ni = 0; ni < 4; ni++)
                acc[mi][ni] = __builtin_amdgcn_mfma_f32_16x16x32_bf16(
                    a[mi], b[ni], acc[mi][ni], 0, 0, 0);
    }

#pragma unroll
    for (int mi = 0; mi < 4; mi++)
#pragma unroll
        for (int ni = 0; ni < 4; ni++) {
            int n = n0 + wc * 64 + ni * 16 + fr;
            float bv_ = bp[n];
#pragma unroll
            for (int r = 0; r < 4; r++) {
                int m = m0 + wr * 64 + mi * 16 + fg * 4 + r;
                out[(size_t)m * CC + n] = acc[mi][ni][r] + bv_;
            }
        }
}

// ---------------------------------------------------------------------------
// Flash attention, tiled-causal mask: valid iff (j%512) <= (i%512).
// 4 independent waves x 16 Q-rows; K chunks of 32; NO barriers, NO K/V LDS
// staging (K/V are L2-resident per (b,h)); V comes in pre-transposed [B,H,D,T].
// Only LDS use: tiny per-wave P-relayout buffer (stride 36 -> <=2-way banks).
// q pre-scaled by 1/sqrt(D). Writes y as bf16 [B,T,C].
// ---------------------------------------------------------------------------
__global__ __launch_bounds__(256) void attn(
    const unsigned short* __restrict__ q, const unsigned short* __restrict__ k,
    const unsigned short* __restrict__ vt, unsigned short* __restrict__ y) {
    __shared__ unsigned short Ps[4][16][36];    // per-wave P relayout buffer

    const int bh = blockIdx.y;                  // b*NH + h
    const int q0 = blockIdx.x * 64;
    const int tid = threadIdx.x;
    const int w = tid >> 6;
    const int lane = tid & 63;
    const int fr = lane & 15, fg = lane >> 4;

    const size_t base = (size_t)bh * TT * HD;

    // Q fragments, resident whole kernel: rows q0+w*16+fr, d = s*32 + fg*8..+7
    bf16x8 aq[2];
#pragma unroll
    for (int s = 0; s < 2; s++)
        aq[s] = *reinterpret_cast<const bf16x8*>(
            &q[base + (size_t)(q0 + w * 16 + fr) * HD + s * 32 + fg * 8]);

    f32x4 acc_o[4];
#pragma unroll
    for (int i = 0; i < 4; i++) acc_o[i] = (f32x4){0.f, 0.f, 0.f, 0.f};
    float mrow[4] = {-1e30f, -1e30f, -1e30f, -1e30f};
    float lrow[4] = {0.f, 0.f, 0.f, 0.f};

    const int qb = q0 & 511;
    const int nfull = qb >> 5;   // chunks per 512-segment with kb+31 <= qb

    auto body = [&](int k0, bool partial) {
        const int kb = k0 & 511;
        // S = Q K^T: B-fragments straight from global (L2-hit)
        f32x4 S[2];
#pragma unroll
        for (int nb = 0; nb < 2; nb++) {
            f32x4 sa = (f32x4){0.f, 0.f, 0.f, 0.f};
#pragma unroll
            for (int s = 0; s < 2; s++) {
                bf16x8 bk_ = *reinterpret_cast<const bf16x8*>(
                    &k[base + (size_t)(k0 + nb * 16 + fr) * HD + s * 32 + fg * 8]);
                sa = __builtin_amdgcn_mfma_f32_16x16x32_bf16(aq[s], bk_, sa, 0, 0, 0);
            }
            S[nb] = sa;
        }

        if (partial) {
#pragma unroll
            for (int nb = 0; nb < 2; nb++)
#pragma unroll
                for (int r = 0; r < 4; r++) {
                    int ib = qb + w * 16 + fg * 4 + r;
                    int jb = kb + nb * 16 + fr;
                    if (jb > ib) S[nb][r] = -1e30f;
                }
        }

        // online softmax (each row lives across 16 consecutive lanes)
        float psc[4];
#pragma unroll
        for (int r = 0; r < 4; r++) {
            float mr = fmaxf(S[0][r], S[1][r]);
#pragma unroll
            for (int off = 1; off < 16; off <<= 1) mr = fmaxf(mr, __shfl_xor(mr, off));
            float mnew = fmaxf(mrow[r], mr);
            float p0 = __expf(S[0][r] - mnew);
            float p1 = __expf(S[1][r] - mnew);
            float sc = __expf(mrow[r] - mnew);
            S[0][r] = p0;
            S[1][r] = p1;
            float rs = p0 + p1;
#pragma unroll
            for (int off = 1; off < 16; off <<= 1) rs += __shfl_xor(rs, off);
            lrow[r] = lrow[r] * sc + rs;
            mrow[r] = mnew;
            psc[r] = sc;
        }
#pragma unroll
        for (int nd = 0; nd < 4; nd++)
#pragma unroll
            for (int r = 0; r < 4; r++) acc_o[nd][r] *= psc[r];

        // P (C-layout) -> LDS -> A-fragment layout (same wave, in-order DS)
#pragma unroll
        for (int nb = 0; nb < 2; nb++)
#pragma unroll
            for (int r = 0; r < 4; r++)
                Ps[w][fg * 4 + r][nb * 16 + fr] = f2bf(S[nb][r]);

        bf16x8 ap = *reinterpret_cast<const bf16x8*>(&Ps[w][fr][fg * 8]);
#pragma unroll
        for (int nd = 0; nd < 4; nd++) {
            // V^T fragment straight from global: row d = nd*16+fr, t = k0+fg*8
            bf16x8 bv_ = *reinterpret_cast<const bf16x8*>(
                &vt[base + (size_t)(nd * 16 + fr) * TT + k0 + fg * 8]);
            acc_o[nd] = __builtin_amdgcn_mfma_f32_16x16x32_bf16(ap, bv_, acc_o[nd], 0, 0, 0);
        }
    };

    for (int s = 0; s < 3; s++) {
        const int kseg = s * 512;
        for (int c = 0; c < nfull; c++) body(kseg + c * 32, false);
        body(kseg + nfull * 32, true);        // kb = qb
        body(kseg + nfull * 32 + 32, true);   // kb = qb + 32
    }

    // finalize: y[b][t][h*64+d] bf16
    const int b_ = bh / NH, h = bh % NH;
#pragma unroll
    for (int r = 0; r < 4; r++) {
        float inv = 1.f / lrow[r];
        int t = q0 + w * 16 + fg * 4 + r;
        size_t off = ((size_t)b_ * TT + t) * CC + h * HD;
#pragma unroll
        for (int nd = 0; nd < 4; nd++)
            y[off + nd * 16 + fr] = f2bf(acc_o[nd][r] * inv);
    }
}

extern "C" void kernel_launch(void* const* d_in, const int* in_sizes, int n_in,
                              void* d_out, int out_size, void* d_ws, size_t ws_size,
                              hipStream_t stream) {
    const float* x  = (const float*)d_in[0];
    const float* Wq = (const float*)d_in[1];
    const float* bq = (const float*)d_in[2];
    const float* Wk = (const float*)d_in[3];
    const float* bk = (const float*)d_in[4];
    const float* Wv = (const float*)d_in[5];
    const float* bv = (const float*)d_in[6];
    const float* Wp = (const float*)d_in[7];
    const float* bp = (const float*)d_in[8];
    float* out = (float*)d_out;

    unsigned short* ws  = (unsigned short*)d_ws;
    unsigned short* xb  = ws;                              // MM*CC
    unsigned short* wqb = xb  + (size_t)MM * CC;           // CC*CC each
    unsigned short* wkb = wqb + (size_t)CC * CC;
    unsigned short* wvb = wkb + (size_t)CC * CC;
    unsigned short* wpb = wvb + (size_t)CC * CC;
    unsigned short* qb_ = wpb + (size_t)CC * CC;           // MM*CC each
    unsigned short* kb_ = qb_ + (size_t)MM * CC;
    unsigned short* vt_ = kb_ + (size_t)MM * CC;           // [B,H,D,T]
    unsigned short* yb  = vt_ + (size_t)MM * CC;

    const int n4x = MM * CC / 4, n4w = CC * CC / 4;
    convert_k<<<(n4x + 255) / 256, 256, 0, stream>>>(x, xb, n4x);
    convert_k<<<(n4w + 255) / 256, 256, 0, stream>>>(Wq, wqb, n4w);
    convert_k<<<(n4w + 255) / 256, 256, 0, stream>>>(Wk, wkb, n4w);
    convert_k<<<(n4w + 255) / 256, 256, 0, stream>>>(Wv, wvb, n4w);
    convert_k<<<(n4w + 255) / 256, 256, 0, stream>>>(Wp, wpb, n4w);

    gemm_qkv<<<dim3(CC / 128, MM / 128, 3), 256, 0, stream>>>(
        xb, wqb, bq, wkb, bk, wvb, bv, qb_, kb_, vt_);
    attn<<<dim3(TT / 64, BB * NH), 256, 0, stream>>>(qb_, kb_, vt_, yb);
    gemm_proj<<<dim3(CC / 128, MM / 128), 256, 0, stream>>>(yb, wpb, bp, out);
}

// Round 3
// 268.461 us; speedup vs baseline: 1.3492x; 1.3492x over previous
//
#include <hip/hip_runtime.h>
#include <hip/hip_bf16.h>

typedef __attribute__((ext_vector_type(8))) short bf16x8;
typedef __attribute__((ext_vector_type(4))) float f32x4;

#define NH 12
#define HD 64
#define TT 1536
#define CC 768
#define BB 4
#define MM (BB * TT)   // 6144 rows

__device__ __forceinline__ unsigned short f2bf(float f) {
    unsigned int u = __builtin_bit_cast(unsigned int, f);
    return (unsigned short)((u + 0x7FFFu + ((u >> 16) & 1u)) >> 16);  // RNE
}

__global__ __launch_bounds__(256) void convert_k(const float* __restrict__ in,
                                                 unsigned short* __restrict__ out,
                                                 int n4) {
    int i = blockIdx.x * 256 + threadIdx.x;
    if (i >= n4) return;
    float4 v = reinterpret_cast<const float4*>(in)[i];
    ushort4 o = { f2bf(v.x), f2bf(v.y), f2bf(v.z), f2bf(v.w) };
    reinterpret_cast<ushort4*>(out)[i] = o;
}

// ---------------------------------------------------------------------------
// QKV projection GEMM: C[m,n] = sum_k A[m,k] * W[n,k]  (both K-contiguous)
// tile 128x128, 4 waves (each 64x64), BK=32, 16x16x32 bf16 MFMA.
// Epilogue: q -> [B,H,T,D] scaled 0.125; k -> [B,H,T,D]; v -> [B,H,D,T] (transposed!)
// ---------------------------------------------------------------------------
__global__ __launch_bounds__(256) void gemm_qkv(
    const unsigned short* __restrict__ xb,
    const unsigned short* __restrict__ wq, const float* __restrict__ bq,
    const unsigned short* __restrict__ wk, const float* __restrict__ bk,
    const unsigned short* __restrict__ wv, const float* __restrict__ bv,
    unsigned short* __restrict__ qo, unsigned short* __restrict__ ko,
    unsigned short* __restrict__ vo) {
    __shared__ unsigned short As[128][40];
    __shared__ unsigned short Bs[128][40];

    const int z = blockIdx.z;
    const unsigned short* W = (z == 0) ? wq : (z == 1) ? wk : wv;
    const float* bias = (z == 0) ? bq : (z == 1) ? bk : bv;
    unsigned short* out = (z == 0) ? qo : (z == 1) ? ko : vo;
    const float scale = (z == 0) ? 0.125f : 1.0f;

    const int m0 = blockIdx.y * 128;
    const int n0 = blockIdx.x * 128;
    const int tid = threadIdx.x;
    const int lane = tid & 63;
    const int w = tid >> 6;
    const int wr = w >> 1, wc = w & 1;
    const int fr = lane & 15, fg = lane >> 4;

    f32x4 acc[4][4];
#pragma unroll
    for (int i = 0; i < 4; i++)
#pragma unroll
        for (int j = 0; j < 4; j++) acc[i][j] = (f32x4){0.f, 0.f, 0.f, 0.f};

    for (int k0 = 0; k0 < CC; k0 += 32) {
        __syncthreads();
        for (int c = tid; c < 512; c += 256) {
            int row = c >> 2, cg = c & 3;
            *reinterpret_cast<uint4*>(&As[row][cg * 8]) =
                *reinterpret_cast<const uint4*>(&xb[(size_t)(m0 + row) * CC + k0 + cg * 8]);
            *reinterpret_cast<uint4*>(&Bs[row][cg * 8]) =
                *reinterpret_cast<const uint4*>(&W[(size_t)(n0 + row) * CC + k0 + cg * 8]);
        }
        __syncthreads();
        bf16x8 a[4], b[4];
#pragma unroll
        for (int mi = 0; mi < 4; mi++)
            a[mi] = *reinterpret_cast<const bf16x8*>(&As[wr * 64 + mi * 16 + fr][fg * 8]);
#pragma unroll
        for (int ni = 0; ni < 4; ni++)
            b[ni] = *reinterpret_cast<const bf16x8*>(&Bs[wc * 64 + ni * 16 + fr][fg * 8]);
#pragma unroll
        for (int mi = 0; mi < 4; mi++)
#pragma unroll
            for (int ni = 0; ni < 4; ni++)
                acc[mi][ni] = __builtin_amdgcn_mfma_f32_16x16x32_bf16(
                    a[mi], b[ni], acc[mi][ni], 0, 0, 0);
    }

#pragma unroll
    for (int mi = 0; mi < 4; mi++)
#pragma unroll
        for (int ni = 0; ni < 4; ni++) {
            int n = n0 + wc * 64 + ni * 16 + fr;
            int h = n >> 6, d = n & 63;
            float bv_ = bias[n];
            int m_base = m0 + wr * 64 + mi * 16 + fg * 4;
            int b_ = m_base / TT, t0 = m_base % TT;
            if (z == 2) {
                size_t off = ((size_t)(b_ * NH + h) * HD + d) * (size_t)TT + t0;
                ushort4 o = { f2bf(acc[mi][ni][0] + bv_), f2bf(acc[mi][ni][1] + bv_),
                              f2bf(acc[mi][ni][2] + bv_), f2bf(acc[mi][ni][3] + bv_) };
                *reinterpret_cast<ushort4*>(&out[off]) = o;
            } else {
#pragma unroll
                for (int r = 0; r < 4; r++) {
                    size_t off = ((size_t)(b_ * NH + h) * TT + t0 + r) * (size_t)HD + d;
                    out[off] = f2bf((acc[mi][ni][r] + bv_) * scale);
                }
            }
        }
}

// ---------------------------------------------------------------------------
// Output projection GEMM: same structure, fp32 output [M, C] = d_out.
// ---------------------------------------------------------------------------
__global__ __launch_bounds__(256) void gemm_proj(
    const unsigned short* __restrict__ yb,
    const unsigned short* __restrict__ wp, const float* __restrict__ bp,
    float* __restrict__ out) {
    __shared__ unsigned short As[128][40];
    __shared__ unsigned short Bs[128][40];

    const int m0 = blockIdx.y * 128;
    const int n0 = blockIdx.x * 128;
    const int tid = threadIdx.x;
    const int lane = tid & 63;
    const int w = tid >> 6;
    const int wr = w >> 1, wc = w & 1;
    const int fr = lane & 15, fg = lane >> 4;

    f32x4 acc[4][4];
#pragma unroll
    for (int i = 0; i < 4; i++)
#pragma unroll
        for (int j = 0; j < 4; j++) acc[i][j] = (f32x4){0.f, 0.f, 0.f, 0.f};

    for (int k0 = 0; k0 < CC; k0 += 32) {
        __syncthreads();
        for (int c = tid; c < 512; c += 256) {
            int row = c >> 2, cg = c & 3;
            *reinterpret_cast<uint4*>(&As[row][cg * 8]) =
                *reinterpret_cast<const uint4*>(&yb[(size_t)(m0 + row) * CC + k0 + cg * 8]);
            *reinterpret_cast<uint4*>(&Bs[row][cg * 8]) =
                *reinterpret_cast<const uint4*>(&wp[(size_t)(n0 + row) * CC + k0 + cg * 8]);
        }
        __syncthreads();
        bf16x8 a[4], b[4];
#pragma unroll
        for (int mi = 0; mi < 4; mi++)
            a[mi] = *reinterpret_cast<const bf16x8*>(&As[wr * 64 + mi * 16 + fr][fg * 8]);
#pragma unroll
        for (int ni = 0; ni < 4; ni++)
            b[ni] = *reinterpret_cast<const bf16x8*>(&Bs[wc * 64 + ni * 16 + fr][fg * 8]);
#pragma unroll
        for (int mi = 0; mi < 4; mi++)
#pragma unroll
            for (int ni = 0; ni < 4; ni++)
                acc[mi][ni] = __builtin_amdgcn_mfma_f32_16x16x32_bf16(
                    a[mi], b[ni], acc[mi][ni], 0, 0, 0);
    }

#pragma unroll
    for (int mi = 0; mi < 4; mi++)
#pragma unroll
        for (int ni = 0; ni < 4; ni++) {
            int n = n0 + wc * 64 + ni * 16 + fr;
            float bv_ = bp[n];
#pragma unroll
            for (int r = 0; r < 4; r++) {
                int m = m0 + wr * 64 + mi * 16 + fg * 4 + r;
                out[(size_t)m * CC + n] = acc[mi][ni][r] + bv_;
            }
        }
}

// ---------------------------------------------------------------------------
// Flash attention, tiled-causal mask: valid iff (j%512) <= (i%512).
// 4 waves x 16 Q-rows = 64 rows/block; K-chunks of 64 keys; K and V^T staged
// in double-buffered LDS (stride 72 shorts = even bank spread, 16B aligned);
// one __syncthreads per chunk; next chunk's global loads issued into regs
// BEFORE compute (T14 async-stage split). q pre-scaled by 1/sqrt(D).
// ---------------------------------------------------------------------------
__global__ __launch_bounds__(256) void attn(
    const unsigned short* __restrict__ q, const unsigned short* __restrict__ k,
    const unsigned short* __restrict__ vt, unsigned short* __restrict__ y) {
    __shared__ unsigned short Ks[2][64][72];
    __shared__ unsigned short Vs[2][64][72];
    __shared__ unsigned short Ps[4][16][72];

    const int bh = blockIdx.y;                  // b*NH + h
    const int q0 = blockIdx.x * 64;
    const int tid = threadIdx.x;
    const int w = tid >> 6;
    const int lane = tid & 63;
    const int fr = lane & 15, fg = lane >> 4;

    const size_t base = (size_t)bh * TT * HD;

    // Q fragments resident whole kernel: rows q0+w*16+fr, d = s*32+fg*8..+7
    bf16x8 aq[2];
#pragma unroll
    for (int s = 0; s < 2; s++)
        aq[s] = *reinterpret_cast<const bf16x8*>(
            &q[base + (size_t)(q0 + w * 16 + fr) * HD + s * 32 + fg * 8]);

    f32x4 acc_o[4];
#pragma unroll
    for (int i = 0; i < 4; i++) acc_o[i] = (f32x4){0.f, 0.f, 0.f, 0.f};
    float mrow[4] = {-1e30f, -1e30f, -1e30f, -1e30f};
    float lrow[4] = {0.f, 0.f, 0.f, 0.f};

    // staging: thread covers row r0, 32B (2 uint4) at colgroup cg0 of a
    // 64x64-bf16 tile (8 uint4 per row)
    const int r0 = tid >> 2;
    const int cg0 = (tid & 3) * 2;

    uint4 kreg[2], vreg[2];
    auto issue = [&](int k0n) {
        const unsigned short* kp = &k[base + (size_t)(k0n + r0) * HD + cg0 * 8];
        kreg[0] = *reinterpret_cast<const uint4*>(kp);
        kreg[1] = *reinterpret_cast<const uint4*>(kp + 8);
        const unsigned short* vp = &vt[base + (size_t)r0 * TT + k0n + cg0 * 8];
        vreg[0] = *reinterpret_cast<const uint4*>(vp);
        vreg[1] = *reinterpret_cast<const uint4*>(vp + 8);
    };
    auto wlds = [&](int b) {
        *reinterpret_cast<uint4*>(&Ks[b][r0][cg0 * 8]) = kreg[0];
        *reinterpret_cast<uint4*>(&Ks[b][r0][cg0 * 8 + 8]) = kreg[1];
        *reinterpret_cast<uint4*>(&Vs[b][r0][cg0 * 8]) = vreg[0];
        *reinterpret_cast<uint4*>(&Vs[b][r0][cg0 * 8 + 8]) = vreg[1];
    };

    const int qb = q0 & 511;
    const int nfull = qb >> 6;        // full 64-chunks per 512-segment
    const int per = nfull + 1;        // + diagonal partial chunk
    const int ntot = 3 * per;

    issue(0);
    wlds(0);
    int cur = 0;
    int seg = 0, j = 0;               // current chunk coords
    int seg2 = 0, j2 = 0;             // next chunk coords

    for (int ci = 0; ci < ntot; ci++) {
        const int k0 = seg * 512 + j * 64;
        const bool partial = (j == nfull);
        if (ci + 1 < ntot) {
            j2++; if (j2 == per) { j2 = 0; seg2++; }
            issue(seg2 * 512 + j2 * 64);
        }
        __syncthreads();              // buf[cur] writes visible to all waves

        // S = Q K^T : 16 q-rows x 64 keys per wave
        f32x4 S[4];
#pragma unroll
        for (int nb = 0; nb < 4; nb++) {
            f32x4 sa = (f32x4){0.f, 0.f, 0.f, 0.f};
#pragma unroll
            for (int s = 0; s < 2; s++) {
                bf16x8 bk_ = *reinterpret_cast<const bf16x8*>(
                    &Ks[cur][nb * 16 + fr][s * 32 + fg * 8]);
                sa = __builtin_amdgcn_mfma_f32_16x16x32_bf16(aq[s], bk_, sa, 0, 0, 0);
            }
            S[nb] = sa;
        }

        if (partial) {                // diagonal 64x64 block: elementwise mask
#pragma unroll
            for (int nb = 0; nb < 4; nb++)
#pragma unroll
                for (int r = 0; r < 4; r++) {
                    int ib = w * 16 + fg * 4 + r;      // q row within block
                    int jb = nb * 16 + fr;             // key within chunk
                    if (jb > ib) S[nb][r] = -1e30f;
                }
        }

        // online softmax (each row lives across 16 consecutive lanes)
        float psc[4];
#pragma unroll
        for (int r = 0; r < 4; r++) {
            float mr = fmaxf(fmaxf(S[0][r], S[1][r]), fmaxf(S[2][r], S[3][r]));
#pragma unroll
            for (int off = 1; off < 16; off <<= 1) mr = fmaxf(mr, __shfl_xor(mr, off));
            float mnew = fmaxf(mrow[r], mr);
            float sc = __expf(mrow[r] - mnew);
            float rs = 0.f;
#pragma unroll
            for (int nb = 0; nb < 4; nb++) {
                float p = __expf(S[nb][r] - mnew);
                S[nb][r] = p;
                rs += p;
            }
#pragma unroll
            for (int off = 1; off < 16; off <<= 1) rs += __shfl_xor(rs, off);
            lrow[r] = lrow[r] * sc + rs;
            mrow[r] = mnew;
            psc[r] = sc;
        }
#pragma unroll
        for (int nd = 0; nd < 4; nd++)
#pragma unroll
            for (int r = 0; r < 4; r++) acc_o[nd][r] *= psc[r];

        // P (C-layout) -> LDS -> A-fragment layout (same wave, in-order DS)
#pragma unroll
        for (int nb = 0; nb < 4; nb++)
#pragma unroll
            for (int r = 0; r < 4; r++)
                Ps[w][fg * 4 + r][nb * 16 + fr] = f2bf(S[nb][r]);

        bf16x8 ap[2];
#pragma unroll
        for (int ks = 0; ks < 2; ks++)
            ap[ks] = *reinterpret_cast<const bf16x8*>(&Ps[w][fr][ks * 32 + fg * 8]);
#pragma unroll
        for (int nd = 0; nd < 4; nd++)
#pragma unroll
            for (int ks = 0; ks < 2; ks++) {
                bf16x8 bv_ = *reinterpret_cast<const bf16x8*>(
                    &Vs[cur][nd * 16 + fr][ks * 32 + fg * 8]);
                acc_o[nd] = __builtin_amdgcn_mfma_f32_16x16x32_bf16(
                    ap[ks], bv_, acc_o[nd], 0, 0, 0);
            }

        if (ci + 1 < ntot) wlds(cur ^ 1);   // safe: readers of cur^1 were
        cur ^= 1;                           // separated by this iter's barrier
        seg = seg2; j = j2;
    }

    // finalize: y[b][t][h*64+d] bf16
    const int b_ = bh / NH, h = bh % NH;
#pragma unroll
    for (int r = 0; r < 4; r++) {
        float inv = 1.f / lrow[r];
        int t = q0 + w * 16 + fg * 4 + r;
        size_t off = ((size_t)b_ * TT + t) * CC + h * HD;
#pragma unroll
        for (int nd = 0; nd < 4; nd++)
            y[off + nd * 16 + fr] = f2bf(acc_o[nd][r] * inv);
    }
}

extern "C" void kernel_launch(void* const* d_in, const int* in_sizes, int n_in,
                              void* d_out, int out_size, void* d_ws, size_t ws_size,
                              hipStream_t stream) {
    const float* x  = (const float*)d_in[0];
    const float* Wq = (const float*)d_in[1];
    const float* bq = (const float*)d_in[2];
    const float* Wk = (const float*)d_in[3];
    const float* bk = (const float*)d_in[4];
    const float* Wv = (const float*)d_in[5];
    const float* bv = (const float*)d_in[6];
    const float* Wp = (const float*)d_in[7];
    const float* bp = (const float*)d_in[8];
    float* out = (float*)d_out;

    unsigned short* ws  = (unsigned short*)d_ws;
    unsigned short* xb  = ws;                              // MM*CC
    unsigned short* wqb = xb  + (size_t)MM * CC;           // CC*CC each
    unsigned short* wkb = wqb + (size_t)CC * CC;
    unsigned short* wvb = wkb + (size_t)CC * CC;
    unsigned short* wpb = wvb + (size_t)CC * CC;
    unsigned short* qb_ = wpb + (size_t)CC * CC;           // MM*CC each
    unsigned short* kb_ = qb_ + (size_t)MM * CC;
    unsigned short* vt_ = kb_ + (size_t)MM * CC;           // [B,H,D,T]
    unsigned short* yb  = vt_ + (size_t)MM * CC;

    const int n4x = MM * CC / 4, n4w = CC * CC / 4;
    convert_k<<<(n4x + 255) / 256, 256, 0, stream>>>(x, xb, n4x);
    convert_k<<<(n4w + 255) / 256, 256, 0, stream>>>(Wq, wqb, n4w);
    convert_k<<<(n4w + 255) / 256, 256, 0, stream>>>(Wk, wkb, n4w);
    convert_k<<<(n4w + 255) / 256, 256, 0, stream>>>(Wv, wvb, n4w);
    convert_k<<<(n4w + 255) / 256, 256, 0, stream>>>(Wp, wpb, n4w);

    gemm_qkv<<<dim3(CC / 128, MM / 128, 3), 256, 0, stream>>>(
        xb, wqb, bq, wkb, bk, wvb, bv, qb_, kb_, vt_);
    attn<<<dim3(TT / 64, BB * NH), 256, 0, stream>>>(qb_, kb_, vt_, yb);
    gemm_proj<<<dim3(CC / 128, MM / 128), 256, 0, stream>>>(yb, wpb, bp, out);
}

// Round 6
// 214.554 us; speedup vs baseline: 1.6882x; 1.2513x over previous
//
#include <hip/hip_runtime.h>
#include <hip/hip_bf16.h>

typedef __attribute__((ext_vector_type(8))) short bf16x8;
typedef __attribute__((ext_vector_type(4))) float f32x4;

#define NH 12
#define HD 64
#define TT 1536
#define CC 768
#define BB 4
#define MM (BB * TT)   // 6144 rows

__device__ __forceinline__ unsigned short f2bf(float f) {
    unsigned int u = __builtin_bit_cast(unsigned int, f);
    return (unsigned short)((u + 0x7FFFu + ((u >> 16) & 1u)) >> 16);  // RNE
}

// one launch converting all four weight matrices fp32 -> bf16
__global__ __launch_bounds__(256) void convert_w4(
    const float* __restrict__ w0, const float* __restrict__ w1,
    const float* __restrict__ w2, const float* __restrict__ w3,
    unsigned short* __restrict__ o0, unsigned short* __restrict__ o1,
    unsigned short* __restrict__ o2, unsigned short* __restrict__ o3, int n4) {
    int i = blockIdx.x * 256 + threadIdx.x;
    if (i >= n4) return;
    const float* in = blockIdx.y == 0 ? w0 : blockIdx.y == 1 ? w1
                    : blockIdx.y == 2 ? w2 : w3;
    unsigned short* out = blockIdx.y == 0 ? o0 : blockIdx.y == 1 ? o1
                        : blockIdx.y == 2 ? o2 : o3;
    float4 v = reinterpret_cast<const float4*>(in)[i];
    ushort4 o = { f2bf(v.x), f2bf(v.y), f2bf(v.z), f2bf(v.w) };
    reinterpret_cast<ushort4*>(out)[i] = o;
}

// ---------------------------------------------------------------------------
// QKV projection GEMM; A-operand staged DIRECTLY from fp32 x (fused convert).
// q -> [B,H,T,D] scaled 0.125; k -> [B,H,T,D]; v -> [B,H,D,T] (transposed)
// ---------------------------------------------------------------------------
__global__ __launch_bounds__(256) void gemm_qkv(
    const float* __restrict__ xf,
    const unsigned short* __restrict__ wq, const float* __restrict__ bq,
    const unsigned short* __restrict__ wk, const float* __restrict__ bk,
    const unsigned short* __restrict__ wv, const float* __restrict__ bv,
    unsigned short* __restrict__ qo, unsigned short* __restrict__ ko,
    unsigned short* __restrict__ vo) {
    __shared__ unsigned short As[128][40];
    __shared__ unsigned short Bs[128][40];

    const int z = blockIdx.z;
    const unsigned short* W = (z == 0) ? wq : (z == 1) ? wk : wv;
    const float* bias = (z == 0) ? bq : (z == 1) ? bk : bv;
    unsigned short* out = (z == 0) ? qo : (z == 1) ? ko : vo;
    const float scale = (z == 0) ? 0.125f : 1.0f;

    const int m0 = blockIdx.y * 128;
    const int n0 = blockIdx.x * 128;
    const int tid = threadIdx.x;
    const int lane = tid & 63;
    const int w = tid >> 6;
    const int wr = w >> 1, wc = w & 1;
    const int fr = lane & 15, fg = lane >> 4;

    f32x4 acc[4][4];
#pragma unroll
    for (int i = 0; i < 4; i++)
#pragma unroll
        for (int j = 0; j < 4; j++) acc[i][j] = (f32x4){0.f, 0.f, 0.f, 0.f};

    for (int k0 = 0; k0 < CC; k0 += 32) {
        __syncthreads();
        for (int c = tid; c < 512; c += 256) {
            int row = c >> 2, cg = c & 3;
            const float* xp = &xf[(size_t)(m0 + row) * CC + k0 + cg * 8];
            float4 f0 = *reinterpret_cast<const float4*>(xp);
            float4 f1 = *reinterpret_cast<const float4*>(xp + 4);
            ushort4 h0 = { f2bf(f0.x), f2bf(f0.y), f2bf(f0.z), f2bf(f0.w) };
            ushort4 h1 = { f2bf(f1.x), f2bf(f1.y), f2bf(f1.z), f2bf(f1.w) };
            *reinterpret_cast<ushort4*>(&As[row][cg * 8]) = h0;
            *reinterpret_cast<ushort4*>(&As[row][cg * 8 + 4]) = h1;
            *reinterpret_cast<uint4*>(&Bs[row][cg * 8]) =
                *reinterpret_cast<const uint4*>(&W[(size_t)(n0 + row) * CC + k0 + cg * 8]);
        }
        __syncthreads();
        bf16x8 a[4], b[4];
#pragma unroll
        for (int mi = 0; mi < 4; mi++)
            a[mi] = *reinterpret_cast<const bf16x8*>(&As[wr * 64 + mi * 16 + fr][fg * 8]);
#pragma unroll
        for (int ni = 0; ni < 4; ni++)
            b[ni] = *reinterpret_cast<const bf16x8*>(&Bs[wc * 64 + ni * 16 + fr][fg * 8]);
#pragma unroll
        for (int mi = 0; mi < 4; mi++)
#pragma unroll
            for (int ni = 0; ni < 4; ni++)
                acc[mi][ni] = __builtin_amdgcn_mfma_f32_16x16x32_bf16(
                    a[mi], b[ni], acc[mi][ni], 0, 0, 0);
    }

#pragma unroll
    for (int mi = 0; mi < 4; mi++)
#pragma unroll
        for (int ni = 0; ni < 4; ni++) {
            int n = n0 + wc * 64 + ni * 16 + fr;
            int h = n >> 6, d = n & 63;
            float bv_ = bias[n];
            int m_base = m0 + wr * 64 + mi * 16 + fg * 4;
            int b_ = m_base / TT, t0 = m_base % TT;
            if (z == 2) {
                size_t off = ((size_t)(b_ * NH + h) * HD + d) * (size_t)TT + t0;
                ushort4 o = { f2bf(acc[mi][ni][0] + bv_), f2bf(acc[mi][ni][1] + bv_),
                              f2bf(acc[mi][ni][2] + bv_), f2bf(acc[mi][ni][3] + bv_) };
                *reinterpret_cast<ushort4*>(&out[off]) = o;
            } else {
#pragma unroll
                for (int r = 0; r < 4; r++) {
                    size_t off = ((size_t)(b_ * NH + h) * TT + t0 + r) * (size_t)HD + d;
                    out[off] = f2bf((acc[mi][ni][r] + bv_) * scale);
                }
            }
        }
}

// ---------------------------------------------------------------------------
// Output projection GEMM (unchanged): fp32 output [M, C] = d_out.
// ---------------------------------------------------------------------------
__global__ __launch_bounds__(256) void gemm_proj(
    const unsigned short* __restrict__ yb,
    const unsigned short* __restrict__ wp, const float* __restrict__ bp,
    float* __restrict__ out) {
    __shared__ unsigned short As[128][40];
    __shared__ unsigned short Bs[128][40];

    const int m0 = blockIdx.y * 128;
    const int n0 = blockIdx.x * 128;
    const int tid = threadIdx.x;
    const int lane = tid & 63;
    const int w = tid >> 6;
    const int wr = w >> 1, wc = w & 1;
    const int fr = lane & 15, fg = lane >> 4;

    f32x4 acc[4][4];
#pragma unroll
    for (int i = 0; i < 4; i++)
#pragma unroll
        for (int j = 0; j < 4; j++) acc[i][j] = (f32x4){0.f, 0.f, 0.f, 0.f};

    for (int k0 = 0; k0 < CC; k0 += 32) {
        __syncthreads();
        for (int c = tid; c < 512; c += 256) {
            int row = c >> 2, cg = c & 3;
            *reinterpret_cast<uint4*>(&As[row][cg * 8]) =
                *reinterpret_cast<const uint4*>(&yb[(size_t)(m0 + row) * CC + k0 + cg * 8]);
            *reinterpret_cast<uint4*>(&Bs[row][cg * 8]) =
                *reinterpret_cast<const uint4*>(&wp[(size_t)(n0 + row) * CC + k0 + cg * 8]);
        }
        __syncthreads();
        bf16x8 a[4], b[4];
#pragma unroll
        for (int mi = 0; mi < 4; mi++)
            a[mi] = *reinterpret_cast<const bf16x8*>(&As[wr * 64 + mi * 16 + fr][fg * 8]);
#pragma unroll
        for (int ni = 0; ni < 4; ni++)
            b[ni] = *reinterpret_cast<const bf16x8*>(&Bs[wc * 64 + ni * 16 + fr][fg * 8]);
#pragma unroll
        for (int mi = 0; mi < 4; mi++)
#pragma unroll
            for (int ni = 0; ni < 4; ni++)
                acc[mi][ni] = __builtin_amdgcn_mfma_f32_16x16x32_bf16(
                    a[mi], b[ni], acc[mi][ni], 0, 0, 0);
    }

#pragma unroll
    for (int mi = 0; mi < 4; mi++)
#pragma unroll
        for (int ni = 0; ni < 4; ni++) {
            int n = n0 + wc * 64 + ni * 16 + fr;
            float bv_ = bp[n];
#pragma unroll
            for (int r = 0; r < 4; r++) {
                int m = m0 + wr * 64 + mi * 16 + fg * 4 + r;
                out[(size_t)m * CC + n] = acc[mi][ni][r] + bv_;
            }
        }
}

// ---------------------------------------------------------------------------
// Flash attention (R3-proven dataflow) with SHUFFLE-FREE fixed-shift softmax:
//   p = exp(S - 10)   (|S| <= ~8 for normalized inputs -> safe, exact softmax
//                      up to fp rounding; no running max, no O-rescale)
//   row-sum l via ones-vector MFMA: acc_l = mfma(P, ones) -> l lands per-lane.
// 4 waves x 16 Q-rows, 64-key chunks, double-buffered K/V^T LDS staging,
// one barrier per chunk, register prefetch one chunk ahead. Heavy tiles first.
// Mask: valid iff (j%512) <= (i%512); q pre-scaled by 1/sqrt(D).
// ---------------------------------------------------------------------------
__global__ __launch_bounds__(256) void attn(
    const unsigned short* __restrict__ q, const unsigned short* __restrict__ k,
    const unsigned short* __restrict__ vt, unsigned short* __restrict__ y) {
    __shared__ unsigned short Ks[2][64][72];
    __shared__ unsigned short Vs[2][64][72];
    __shared__ unsigned short Ps[4][16][72];

    const int bh = blockIdx.y;                  // b*NH + h
    const int qt = blockIdx.x;                  // 0..23, heavy-first
    const int qseg = 7 - qt / 3;                // position within 512-seg, 7..0
    const int sg0 = qt % 3;
    const int q0 = sg0 * 512 + qseg * 64;

    const int tid = threadIdx.x;
    const int w = tid >> 6;
    const int lane = tid & 63;
    const int fr = lane & 15, fg = lane >> 4;

    const size_t base = (size_t)bh * TT * HD;

    // Q fragments resident whole kernel: rows q0+w*16+fr, d = s*32+fg*8..+7
    bf16x8 aq[2];
#pragma unroll
    for (int s = 0; s < 2; s++)
        aq[s] = *reinterpret_cast<const bf16x8*>(
            &q[base + (size_t)(q0 + w * 16 + fr) * HD + s * 32 + fg * 8]);

    f32x4 acc_o[4];
#pragma unroll
    for (int i = 0; i < 4; i++) acc_o[i] = (f32x4){0.f, 0.f, 0.f, 0.f};
    f32x4 acc_l = (f32x4){0.f, 0.f, 0.f, 0.f};

    const bf16x8 ones8 = {(short)0x3F80, (short)0x3F80, (short)0x3F80, (short)0x3F80,
                          (short)0x3F80, (short)0x3F80, (short)0x3F80, (short)0x3F80};

    // staging: thread covers row r0, 32B (2 uint4) at colgroup cg0 of 64x64 tile
    const int r0 = tid >> 2;
    const int cg0 = (tid & 3) * 2;

    uint4 kreg[2], vreg[2];
    auto issue = [&](int k0n) {
        const unsigned short* kp = &k[base + (size_t)(k0n + r0) * HD + cg0 * 8];
        kreg[0] = *reinterpret_cast<const uint4*>(kp);
        kreg[1] = *reinterpret_cast<const uint4*>(kp + 8);
        const unsigned short* vp = &vt[base + (size_t)r0 * TT + k0n + cg0 * 8];
        vreg[0] = *reinterpret_cast<const uint4*>(vp);
        vreg[1] = *reinterpret_cast<const uint4*>(vp + 8);
    };
    auto wlds = [&](int b) {
        *reinterpret_cast<uint4*>(&Ks[b][r0][cg0 * 8]) = kreg[0];
        *reinterpret_cast<uint4*>(&Ks[b][r0][cg0 * 8 + 8]) = kreg[1];
        *reinterpret_cast<uint4*>(&Vs[b][r0][cg0 * 8]) = vreg[0];
        *reinterpret_cast<uint4*>(&Vs[b][r0][cg0 * 8 + 8]) = vreg[1];
    };

    const int nfull = qseg;           // full 64-chunks per 512-segment
    const int per = nfull + 1;        // + diagonal partial chunk
    const int ntot = 3 * per;

    issue(0);
    wlds(0);
    int cur = 0;
    int j = 0;                        // compute-chunk position within segment
    int ji = 0, si = 0;               // last-issued chunk coords

    for (int ci = 0; ci < ntot; ci++) {
        const bool partial = (j == nfull);
        if (ci + 1 < ntot) {
            ji++; if (ji == per) { ji = 0; si++; }
            issue(si * 512 + ji * 64);
        }
        __syncthreads();              // buf[cur] writes visible to all waves

        // S = Q K^T : 16 q-rows x 64 keys per wave
        f32x4 S[4];
#pragma unroll
        for (int nb = 0; nb < 4; nb++) {
            f32x4 sa = (f32x4){0.f, 0.f, 0.f, 0.f};
#pragma unroll
            for (int s = 0; s < 2; s++) {
                bf16x8 bk_ = *reinterpret_cast<const bf16x8*>(
                    &Ks[cur][nb * 16 + fr][s * 32 + fg * 8]);
                sa = __builtin_amdgcn_mfma_f32_16x16x32_bf16(aq[s], bk_, sa, 0, 0, 0);
            }
            S[nb] = sa;
        }

        if (partial) {                // diagonal 64x64 block: elementwise mask
#pragma unroll
            for (int nb = 0; nb < 4; nb++)
#pragma unroll
                for (int r = 0; r < 4; r++) {
                    int ib = w * 16 + fg * 4 + r;      // q row within block
                    int jb = nb * 16 + fr;             // key within chunk
                    if (jb > ib) S[nb][r] = -1e30f;
                }
        }

        // fixed-shift softmax numerator: p = exp(S - 10); no cross-lane ops
#pragma unroll
        for (int nb = 0; nb < 4; nb++)
#pragma unroll
            for (int r = 0; r < 4; r++)
                Ps[w][fg * 4 + r][nb * 16 + fr] = f2bf(__expf(S[nb][r] - 10.f));

        bf16x8 ap[2];
#pragma unroll
        for (int ks = 0; ks < 2; ks++)
            ap[ks] = *reinterpret_cast<const bf16x8*>(&Ps[w][fr][ks * 32 + fg * 8]);
#pragma unroll
        for (int nd = 0; nd < 4; nd++)
#pragma unroll
            for (int ks = 0; ks < 2; ks++) {
                bf16x8 bv_ = *reinterpret_cast<const bf16x8*>(
                    &Vs[cur][nd * 16 + fr][ks * 32 + fg * 8]);
                acc_o[nd] = __builtin_amdgcn_mfma_f32_16x16x32_bf16(
                    ap[ks], bv_, acc_o[nd], 0, 0, 0);
            }
        // row-sum via ones-MFMA: acc_l[r] = sum_keys P[row=fg*4+r][key]
#pragma unroll
        for (int ks = 0; ks < 2; ks++)
            acc_l = __builtin_amdgcn_mfma_f32_16x16x32_bf16(ap[ks], ones8, acc_l, 0, 0, 0);

        if (ci + 1 < ntot) wlds(cur ^ 1);
        cur ^= 1;
        if (++j == per) j = 0;
    }

    // finalize: y[b][t][h*64+d] bf16
    const int b_ = bh / NH, h = bh % NH;
#pragma unroll
    for (int r = 0; r < 4; r++) {
        float inv = 1.f / acc_l[r];
        int t = q0 + w * 16 + fg * 4 + r;
        size_t off = ((size_t)b_ * TT + t) * CC + h * HD;
#pragma unroll
        for (int nd = 0; nd < 4; nd++)
            y[off + nd * 16 + fr] = f2bf(acc_o[nd][r] * inv);
    }
}

extern "C" void kernel_launch(void* const* d_in, const int* in_sizes, int n_in,
                              void* d_out, int out_size, void* d_ws, size_t ws_size,
                              hipStream_t stream) {
    const float* x  = (const float*)d_in[0];
    const float* Wq = (const float*)d_in[1];
    const float* bq = (const float*)d_in[2];
    const float* Wk = (const float*)d_in[3];
    const float* bk = (const float*)d_in[4];
    const float* Wv = (const float*)d_in[5];
    const float* bv = (const float*)d_in[6];
    const float* Wp = (const float*)d_in[7];
    const float* bp = (const float*)d_in[8];
    float* out = (float*)d_out;

    unsigned short* ws  = (unsigned short*)d_ws;
    unsigned short* wqb = ws;                              // CC*CC each
    unsigned short* wkb = wqb + (size_t)CC * CC;
    unsigned short* wvb = wkb + (size_t)CC * CC;
    unsigned short* wpb = wvb + (size_t)CC * CC;
    unsigned short* qb_ = wpb + (size_t)CC * CC;           // MM*CC each
    unsigned short* kb_ = qb_ + (size_t)MM * CC;
    unsigned short* vt_ = kb_ + (size_t)MM * CC;           // [B,H,D,T]
    unsigned short* yb  = vt_ + (size_t)MM * CC;

    const int n4w = CC * CC / 4;
    convert_w4<<<dim3((n4w + 255) / 256, 4), 256, 0, stream>>>(
        Wq, Wk, Wv, Wp, wqb, wkb, wvb, wpb, n4w);

    gemm_qkv<<<dim3(CC / 128, MM / 128, 3), 256, 0, stream>>>(
        x, wqb, bq, wkb, bk, wvb, bv, qb_, kb_, vt_);
    attn<<<dim3(24, BB * NH), 256, 0, stream>>>(qb_, kb_, vt_, yb);
    gemm_proj<<<dim3(CC / 128, MM / 128), 256, 0, stream>>>(yb, wpb, bp, out);
}

// Round 7
// 134.925 us; speedup vs baseline: 2.6846x; 1.5902x over previous
//
#include <hip/hip_runtime.h>
#include <hip/hip_bf16.h>

typedef __attribute__((ext_vector_type(8))) short bf16x8;
typedef __attribute__((ext_vector_type(4))) float f32x4;

#define NH 12
#define HD 64
#define TT 1536
#define CC 768
#define BB 4
#define MM (BB * TT)   // 6144 rows

__device__ __forceinline__ unsigned short f2bf(float f) {
    unsigned int u = __builtin_bit_cast(unsigned int, f);
    return (unsigned short)((u + 0x7FFFu + ((u >> 16) & 1u)) >> 16);  // RNE
}

// async global->LDS, 16B per lane; lds dest = wave-uniform base + lane*16
__device__ __forceinline__ void gl_lds16(const unsigned short* g, unsigned short* l) {
    __builtin_amdgcn_global_load_lds(
        (const __attribute__((address_space(1))) void*)g,
        (__attribute__((address_space(3))) void*)l,
        16, 0, 0);
}

// one launch converting all four weight matrices fp32 -> bf16
__global__ __launch_bounds__(256) void convert_w4(
    const float* __restrict__ w0, const float* __restrict__ w1,
    const float* __restrict__ w2, const float* __restrict__ w3,
    unsigned short* __restrict__ o0, unsigned short* __restrict__ o1,
    unsigned short* __restrict__ o2, unsigned short* __restrict__ o3, int n4) {
    int i = blockIdx.x * 256 + threadIdx.x;
    if (i >= n4) return;
    const float* in = blockIdx.y == 0 ? w0 : blockIdx.y == 1 ? w1
                    : blockIdx.y == 2 ? w2 : w3;
    unsigned short* out = blockIdx.y == 0 ? o0 : blockIdx.y == 1 ? o1
                        : blockIdx.y == 2 ? o2 : o3;
    float4 v = reinterpret_cast<const float4*>(in)[i];
    ushort4 o = { f2bf(v.x), f2bf(v.y), f2bf(v.z), f2bf(v.w) };
    reinterpret_cast<ushort4*>(out)[i] = o;
}

// ---------------------------------------------------------------------------
// QKV projection GEMM; A staged via fused fp32->bf16 convert (regs), B staged
// via global_load_lds width-16 into unpadded [128][32] tiles.
// q -> [B,H,T,D] scaled 0.125; k -> [B,H,T,D]; v -> [B,H,D,T] (transposed)
// ---------------------------------------------------------------------------
__global__ __launch_bounds__(256) void gemm_qkv(
    const float* __restrict__ xf,
    const unsigned short* __restrict__ wq, const float* __restrict__ bq,
    const unsigned short* __restrict__ wk, const float* __restrict__ bk,
    const unsigned short* __restrict__ wv, const float* __restrict__ bv,
    unsigned short* __restrict__ qo, unsigned short* __restrict__ ko,
    unsigned short* __restrict__ vo) {
    __shared__ unsigned short As[128][32];
    __shared__ unsigned short Bs[128][32];

    const int z = blockIdx.z;
    const unsigned short* W = (z == 0) ? wq : (z == 1) ? wk : wv;
    const float* bias = (z == 0) ? bq : (z == 1) ? bk : bv;
    unsigned short* out = (z == 0) ? qo : (z == 1) ? ko : vo;
    const float scale = (z == 0) ? 0.125f : 1.0f;

    const int m0 = blockIdx.y * 128;
    const int n0 = blockIdx.x * 128;
    const int tid = threadIdx.x;
    const int lane = tid & 63;
    const int w = tid >> 6;
    const int wr = w >> 1, wc = w & 1;
    const int fr = lane & 15, fg = lane >> 4;

    // B staging (gload_lds): lane source row/col
    const int br = tid >> 2, bc = (tid & 3) * 8;
    unsigned short* bs0 = &Bs[0][0];
    // A staging (convert): thread covers 16 shorts = half a row
    const int ar = tid >> 1, ah = (tid & 1) * 16;

    f32x4 acc[4][4];
#pragma unroll
    for (int i = 0; i < 4; i++)
#pragma unroll
        for (int j = 0; j < 4; j++) acc[i][j] = (f32x4){0.f, 0.f, 0.f, 0.f};

    for (int k0 = 0; k0 < CC; k0 += 32) {
        __syncthreads();
#pragma unroll
        for (int i = 0; i < 2; i++)
            gl_lds16(&W[(size_t)(n0 + i * 64 + br) * CC + k0 + bc],
                     bs0 + w * 512 + i * 2048);
        {
            const float* xp = &xf[(size_t)(m0 + ar) * CC + k0 + ah];
            float4 f0 = *reinterpret_cast<const float4*>(xp);
            float4 f1 = *reinterpret_cast<const float4*>(xp + 4);
            float4 f2 = *reinterpret_cast<const float4*>(xp + 8);
            float4 f3 = *reinterpret_cast<const float4*>(xp + 12);
            ushort4 h0 = { f2bf(f0.x), f2bf(f0.y), f2bf(f0.z), f2bf(f0.w) };
            ushort4 h1 = { f2bf(f1.x), f2bf(f1.y), f2bf(f1.z), f2bf(f1.w) };
            ushort4 h2 = { f2bf(f2.x), f2bf(f2.y), f2bf(f2.z), f2bf(f2.w) };
            ushort4 h3 = { f2bf(f3.x), f2bf(f3.y), f2bf(f3.z), f2bf(f3.w) };
            *reinterpret_cast<ushort4*>(&As[ar][ah]) = h0;
            *reinterpret_cast<ushort4*>(&As[ar][ah + 4]) = h1;
            *reinterpret_cast<ushort4*>(&As[ar][ah + 8]) = h2;
            *reinterpret_cast<ushort4*>(&As[ar][ah + 12]) = h3;
        }
        __syncthreads();
        bf16x8 a[4], b[4];
#pragma unroll
        for (int mi = 0; mi < 4; mi++)
            a[mi] = *reinterpret_cast<const bf16x8*>(&As[wr * 64 + mi * 16 + fr][fg * 8]);
#pragma unroll
        for (int ni = 0; ni < 4; ni++)
            b[ni] = *reinterpret_cast<const bf16x8*>(&Bs[wc * 64 + ni * 16 + fr][fg * 8]);
#pragma unroll
        for (int mi = 0; mi < 4; mi++)
#pragma unroll
            for (int ni = 0; ni < 4; ni++)
                acc[mi][ni] = __builtin_amdgcn_mfma_f32_16x16x32_bf16(
                    a[mi], b[ni], acc[mi][ni], 0, 0, 0);
    }

#pragma unroll
    for (int mi = 0; mi < 4; mi++)
#pragma unroll
        for (int ni = 0; ni < 4; ni++) {
            int n = n0 + wc * 64 + ni * 16 + fr;
            int h = n >> 6, d = n & 63;
            float bv_ = bias[n];
            int m_base = m0 + wr * 64 + mi * 16 + fg * 4;
            int b_ = m_base / TT, t0 = m_base % TT;
            if (z == 2) {
                size_t off = ((size_t)(b_ * NH + h) * HD + d) * (size_t)TT + t0;
                ushort4 o = { f2bf(acc[mi][ni][0] + bv_), f2bf(acc[mi][ni][1] + bv_),
                              f2bf(acc[mi][ni][2] + bv_), f2bf(acc[mi][ni][3] + bv_) };
                *reinterpret_cast<ushort4*>(&out[off]) = o;
            } else {
#pragma unroll
                for (int r = 0; r < 4; r++) {
                    size_t off = ((size_t)(b_ * NH + h) * TT + t0 + r) * (size_t)HD + d;
                    out[off] = f2bf((acc[mi][ni][r] + bv_) * scale);
                }
            }
        }
}

// ---------------------------------------------------------------------------
// Output projection GEMM: A and B both staged via global_load_lds width-16.
// fp32 output [M, C] = d_out.
// ---------------------------------------------------------------------------
__global__ __launch_bounds__(256) void gemm_proj(
    const unsigned short* __restrict__ yb,
    const unsigned short* __restrict__ wp, const float* __restrict__ bp,
    float* __restrict__ out) {
    __shared__ unsigned short As[128][32];
    __shared__ unsigned short Bs[128][32];

    const int m0 = blockIdx.y * 128;
    const int n0 = blockIdx.x * 128;
    const int tid = threadIdx.x;
    const int lane = tid & 63;
    const int w = tid >> 6;
    const int wr = w >> 1, wc = w & 1;
    const int fr = lane & 15, fg = lane >> 4;

    const int br = tid >> 2, bc = (tid & 3) * 8;
    unsigned short* as0 = &As[0][0];
    unsigned short* bs0 = &Bs[0][0];

    f32x4 acc[4][4];
#pragma unroll
    for (int i = 0; i < 4; i++)
#pragma unroll
        for (int j = 0; j < 4; j++) acc[i][j] = (f32x4){0.f, 0.f, 0.f, 0.f};

    for (int k0 = 0; k0 < CC; k0 += 32) {
        __syncthreads();
#pragma unroll
        for (int i = 0; i < 2; i++) {
            gl_lds16(&yb[(size_t)(m0 + i * 64 + br) * CC + k0 + bc],
                     as0 + w * 512 + i * 2048);
            gl_lds16(&wp[(size_t)(n0 + i * 64 + br) * CC + k0 + bc],
                     bs0 + w * 512 + i * 2048);
        }
        __syncthreads();
        bf16x8 a[4], b[4];
#pragma unroll
        for (int mi = 0; mi < 4; mi++)
            a[mi] = *reinterpret_cast<const bf16x8*>(&As[wr * 64 + mi * 16 + fr][fg * 8]);
#pragma unroll
        for (int ni = 0; ni < 4; ni++)
            b[ni] = *reinterpret_cast<const bf16x8*>(&Bs[wc * 64 + ni * 16 + fr][fg * 8]);
#pragma unroll
        for (int mi = 0; mi < 4; mi++)
#pragma unroll
            for (int ni = 0; ni < 4; ni++)
                acc[mi][ni] = __builtin_amdgcn_mfma_f32_16x16x32_bf16(
                    a[mi], b[ni], acc[mi][ni], 0, 0, 0);
    }

#pragma unroll
    for (int mi = 0; mi < 4; mi++)
#pragma unroll
        for (int ni = 0; ni < 4; ni++) {
            int n = n0 + wc * 64 + ni * 16 + fr;
            float bv_ = bp[n];
#pragma unroll
            for (int r = 0; r < 4; r++) {
                int m = m0 + wr * 64 + mi * 16 + fg * 4 + r;
                out[(size_t)m * CC + n] = acc[mi][ni][r] + bv_;
            }
        }
}

// ---------------------------------------------------------------------------
// Flash attention (R6-proven math) tuned for occupancy + L2 locality:
//  - fixed-shift softmax p=exp(S-10), row-sum via ones-MFMA (no cross-lane ops)
//  - KCHUNK=32, double-buffered K/V^T LDS (1 barrier/chunk), ~25 KB LDS
//  - XOR-swizzled Ps (zero write conflicts)
//  - grid: slot=gid&7 -> 6 (b,h) per XCD slot (K/V L2-resident), heavy-first
// Mask: valid iff (j%512) <= (i%512); q pre-scaled by 1/sqrt(D).
// ---------------------------------------------------------------------------
__global__ __launch_bounds__(256) void attn(
    const unsigned short* __restrict__ q, const unsigned short* __restrict__ k,
    const unsigned short* __restrict__ vt, unsigned short* __restrict__ y) {
    __shared__ unsigned short Ks[2][32][72];
    __shared__ unsigned short Vs[2][64][40];
    __shared__ unsigned short Ps[4][16][40];

    const int gid = blockIdx.x;
    const int slot = gid & 7;
    const int sub = (gid >> 3) % 6;
    const int bh = slot * 6 + sub;              // 6 bh per XCD slot
    const int qt = gid / 48;                    // 0..23, heavy-first
    const int qseg = 7 - qt / 3;                // 7..0
    const int sg0 = qt % 3;
    const int q0 = sg0 * 512 + qseg * 64;

    const int tid = threadIdx.x;
    const int w = tid >> 6;
    const int lane = tid & 63;
    const int fr = lane & 15, fg = lane >> 4;

    const size_t base = (size_t)bh * TT * HD;

    // Q fragments resident whole kernel: rows q0+w*16+fr, d = s*32+fg*8..+7
    bf16x8 aq[2];
#pragma unroll
    for (int s = 0; s < 2; s++)
        aq[s] = *reinterpret_cast<const bf16x8*>(
            &q[base + (size_t)(q0 + w * 16 + fr) * HD + s * 32 + fg * 8]);

    f32x4 acc_o[4];
#pragma unroll
    for (int i = 0; i < 4; i++) acc_o[i] = (f32x4){0.f, 0.f, 0.f, 0.f};
    f32x4 acc_l = (f32x4){0.f, 0.f, 0.f, 0.f};

    const bf16x8 ones8 = {(short)0x3F80, (short)0x3F80, (short)0x3F80, (short)0x3F80,
                          (short)0x3F80, (short)0x3F80, (short)0x3F80, (short)0x3F80};

    // staging: K tile [32][64]: thread -> one uint4; V^T tile [64][32]: one uint4
    const int kr = tid >> 3, kc = tid & 7;
    const int vr = tid >> 2, vc = tid & 3;

    uint4 kreg, vreg;
    auto issue = [&](int k0n) {
        kreg = *reinterpret_cast<const uint4*>(&k[base + (size_t)(k0n + kr) * HD + kc * 8]);
        vreg = *reinterpret_cast<const uint4*>(&vt[base + (size_t)vr * TT + k0n + vc * 8]);
    };
    auto wlds = [&](int b) {
        *reinterpret_cast<uint4*>(&Ks[b][kr][kc * 8]) = kreg;
        *reinterpret_cast<uint4*>(&Vs[b][vr][vc * 8]) = vreg;
    };

    const int per = 2 * qseg + 2;     // 32-key chunks per 512-segment
    const int ntot = 3 * per;

    issue(0);
    wlds(0);
    int cur = 0;
    int j = 0;                        // compute-chunk position within segment
    int ji = 0, si = 0;               // last-issued chunk coords

    for (int ci = 0; ci < ntot; ci++) {
        if (ci + 1 < ntot) {
            ji++; if (ji == per) { ji = 0; si++; }
            issue(si * 512 + ji * 32);
        }
        __syncthreads();              // buf[cur] writes visible to all waves

        // S = Q K^T : 16 q-rows x 32 keys per wave
        f32x4 S[2];
#pragma unroll
        for (int nb = 0; nb < 2; nb++) {
            f32x4 sa = (f32x4){0.f, 0.f, 0.f, 0.f};
#pragma unroll
            for (int s = 0; s < 2; s++) {
                bf16x8 bk_ = *reinterpret_cast<const bf16x8*>(
                    &Ks[cur][nb * 16 + fr][s * 32 + fg * 8]);
                sa = __builtin_amdgcn_mfma_f32_16x16x32_bf16(aq[s], bk_, sa, 0, 0, 0);
            }
            S[nb] = sa;
        }

        if (j >= 2 * qseg) {          // diagonal chunks: elementwise mask
            const int joff = (j - 2 * qseg) * 32;
#pragma unroll
            for (int nb = 0; nb < 2; nb++)
#pragma unroll
                for (int r = 0; r < 4; r++) {
                    int ib = w * 16 + fg * 4 + r;      // q row within 64-tile
                    int jb = joff + nb * 16 + fr;      // key off from qb
                    if (jb > ib) S[nb][r] = -1e30f;
                }
        }

        // fixed-shift softmax numerator -> swizzled Ps (zero-conflict writes)
#pragma unroll
        for (int nb = 0; nb < 2; nb++)
#pragma unroll
            for (int r = 0; r < 4; r++)
                Ps[w][fg * 4 + r][((nb ^ (fg >> 1)) * 16) + fr] =
                    f2bf(__expf(S[nb][r] - 10.f));

        bf16x8 ap = *reinterpret_cast<const bf16x8*>(
            &Ps[w][fr][(fg ^ (2 * (fr >> 3))) * 8]);
#pragma unroll
        for (int nd = 0; nd < 4; nd++) {
            bf16x8 bv_ = *reinterpret_cast<const bf16x8*>(&Vs[cur][nd * 16 + fr][fg * 8]);
            acc_o[nd] = __builtin_amdgcn_mfma_f32_16x16x32_bf16(ap, bv_, acc_o[nd], 0, 0, 0);
        }
        acc_l = __builtin_amdgcn_mfma_f32_16x16x32_bf16(ap, ones8, acc_l, 0, 0, 0);

        if (ci + 1 < ntot) wlds(cur ^ 1);
        cur ^= 1;
        if (++j == per) j = 0;
    }

    // finalize: y[b][t][h*64+d] bf16
    const int b_ = bh / NH, h = bh % NH;
#pragma unroll
    for (int r = 0; r < 4; r++) {
        float inv = 1.f / acc_l[r];
        int t = q0 + w * 16 + fg * 4 + r;
        size_t off = ((size_t)b_ * TT + t) * CC + h * HD;
#pragma unroll
        for (int nd = 0; nd < 4; nd++)
            y[off + nd * 16 + fr] = f2bf(acc_o[nd][r] * inv);
    }
}

extern "C" void kernel_launch(void* const* d_in, const int* in_sizes, int n_in,
                              void* d_out, int out_size, void* d_ws, size_t ws_size,
                              hipStream_t stream) {
    const float* x  = (const float*)d_in[0];
    const float* Wq = (const float*)d_in[1];
    const float* bq = (const float*)d_in[2];
    const float* Wk = (const float*)d_in[3];
    const float* bk = (const float*)d_in[4];
    const float* Wv = (const float*)d_in[5];
    const float* bv = (const float*)d_in[6];
    const float* Wp = (const float*)d_in[7];
    const float* bp = (const float*)d_in[8];
    float* out = (float*)d_out;

    unsigned short* ws  = (unsigned short*)d_ws;
    unsigned short* wqb = ws;                              // CC*CC each
    unsigned short* wkb = wqb + (size_t)CC * CC;
    unsigned short* wvb = wkb + (size_t)CC * CC;
    unsigned short* wpb = wvb + (size_t)CC * CC;
    unsigned short* qb_ = wpb + (size_t)CC * CC;           // MM*CC each
    unsigned short* kb_ = qb_ + (size_t)MM * CC;
    unsigned short* vt_ = kb_ + (size_t)MM * CC;           // [B,H,D,T]
    unsigned short* yb  = vt_ + (size_t)MM * CC;

    const int n4w = CC * CC / 4;
    convert_w4<<<dim3((n4w + 255) / 256, 4), 256, 0, stream>>>(
        Wq, Wk, Wv, Wp, wqb, wkb, wvb, wpb, n4w);

    gemm_qkv<<<dim3(CC / 128, MM / 128, 3), 256, 0, stream>>>(
        x, wqb, bq, wkb, bk, wvb, bv, qb_, kb_, vt_);
    attn<<<dim3(48 * 24), 256, 0, stream>>>(qb_, kb_, vt_, yb);
    gemm_proj<<<dim3(CC / 128, MM / 128), 256, 0, stream>>>(yb, wpb, bp, out);
}

// Round 8
// 115.418 us; speedup vs baseline: 3.1383x; 1.1690x over previous
//
#include <hip/hip_runtime.h>
#include <hip/hip_bf16.h>

typedef __attribute__((ext_vector_type(8))) short bf16x8;
typedef __attribute__((ext_vector_type(4))) float f32x4;

#define NH 12
#define HD 64
#define TT 1536
#define CC 768
#define BB 4
#define MM (BB * TT)   // 6144 rows

__device__ __forceinline__ unsigned short f2bf(float f) {
    unsigned int u = __builtin_bit_cast(unsigned int, f);
    return (unsigned short)((u + 0x7FFFu + ((u >> 16) & 1u)) >> 16);  // RNE
}

// async global->LDS, 16B per lane; lds dest = wave-uniform base + lane*16
__device__ __forceinline__ void gl_lds16(const unsigned short* g, unsigned short* l) {
    __builtin_amdgcn_global_load_lds(
        (const __attribute__((address_space(1))) void*)g,
        (__attribute__((address_space(3))) void*)l,
        16, 0, 0);
}

__global__ __launch_bounds__(256) void convert_x(const float* __restrict__ in,
                                                 unsigned short* __restrict__ out,
                                                 int n4) {
    int i = blockIdx.x * 256 + threadIdx.x;
    if (i >= n4) return;
    float4 v = reinterpret_cast<const float4*>(in)[i];
    ushort4 o = { f2bf(v.x), f2bf(v.y), f2bf(v.z), f2bf(v.w) };
    reinterpret_cast<ushort4*>(out)[i] = o;
}

// one launch converting all four weight matrices fp32 -> bf16
__global__ __launch_bounds__(256) void convert_w4(
    const float* __restrict__ w0, const float* __restrict__ w1,
    const float* __restrict__ w2, const float* __restrict__ w3,
    unsigned short* __restrict__ o0, unsigned short* __restrict__ o1,
    unsigned short* __restrict__ o2, unsigned short* __restrict__ o3, int n4) {
    int i = blockIdx.x * 256 + threadIdx.x;
    if (i >= n4) return;
    const float* in = blockIdx.y == 0 ? w0 : blockIdx.y == 1 ? w1
                    : blockIdx.y == 2 ? w2 : w3;
    unsigned short* out = blockIdx.y == 0 ? o0 : blockIdx.y == 1 ? o1
                        : blockIdx.y == 2 ? o2 : o3;
    float4 v = reinterpret_cast<const float4*>(in)[i];
    ushort4 o = { f2bf(v.x), f2bf(v.y), f2bf(v.z), f2bf(v.w) };
    reinterpret_cast<ushort4*>(out)[i] = o;
}

// ---------------------------------------------------------------------------
// QKV projection GEMM; A and B both staged via global_load_lds width-16.
// 1-D grid, bijective XCD swizzle: 108 consecutive decoded blocks per XCD
// (z=const, 18 m-tiles x 6 n-tiles -> A-panel+weight fit one XCD L2).
// q -> [B,H,T,D] scaled 0.125; k -> [B,H,T,D]; v -> [B,H,D,T] (transposed)
// ---------------------------------------------------------------------------
__global__ __launch_bounds__(256) void gemm_qkv(
    const unsigned short* __restrict__ xb,
    const unsigned short* __restrict__ wq, const float* __restrict__ bq,
    const unsigned short* __restrict__ wk, const float* __restrict__ bk,
    const unsigned short* __restrict__ wv, const float* __restrict__ bv,
    unsigned short* __restrict__ qo, unsigned short* __restrict__ ko,
    unsigned short* __restrict__ vo) {
    __shared__ unsigned short As[128][32];
    __shared__ unsigned short Bs[128][32];

    // bijective XCD swizzle: nwg=864, 108 per XCD
    const int wg = (blockIdx.x & 7) * 108 + (blockIdx.x >> 3);
    const int z = wg / 288;
    const int rem = wg % 288;
    const int m0 = (rem / 6) * 128;
    const int n0 = (rem % 6) * 128;

    const unsigned short* W = (z == 0) ? wq : (z == 1) ? wk : wv;
    const float* bias = (z == 0) ? bq : (z == 1) ? bk : bv;
    unsigned short* out = (z == 0) ? qo : (z == 1) ? ko : vo;
    const float scale = (z == 0) ? 0.125f : 1.0f;

    const int tid = threadIdx.x;
    const int lane = tid & 63;
    const int w = tid >> 6;
    const int wr = w >> 1, wc = w & 1;
    const int fr = lane & 15, fg = lane >> 4;

    const int br = tid >> 2, bc = (tid & 3) * 8;
    unsigned short* as0 = &As[0][0];
    unsigned short* bs0 = &Bs[0][0];

    f32x4 acc[4][4];
#pragma unroll
    for (int i = 0; i < 4; i++)
#pragma unroll
        for (int j = 0; j < 4; j++) acc[i][j] = (f32x4){0.f, 0.f, 0.f, 0.f};

    for (int k0 = 0; k0 < CC; k0 += 32) {
        __syncthreads();
#pragma unroll
        for (int i = 0; i < 2; i++) {
            gl_lds16(&xb[(size_t)(m0 + i * 64 + br) * CC + k0 + bc],
                     as0 + w * 512 + i * 2048);
            gl_lds16(&W[(size_t)(n0 + i * 64 + br) * CC + k0 + bc],
                     bs0 + w * 512 + i * 2048);
        }
        __syncthreads();
        bf16x8 a[4], b[4];
#pragma unroll
        for (int mi = 0; mi < 4; mi++)
            a[mi] = *reinterpret_cast<const bf16x8*>(&As[wr * 64 + mi * 16 + fr][fg * 8]);
#pragma unroll
        for (int ni = 0; ni < 4; ni++)
            b[ni] = *reinterpret_cast<const bf16x8*>(&Bs[wc * 64 + ni * 16 + fr][fg * 8]);
#pragma unroll
        for (int mi = 0; mi < 4; mi++)
#pragma unroll
            for (int ni = 0; ni < 4; ni++)
                acc[mi][ni] = __builtin_amdgcn_mfma_f32_16x16x32_bf16(
                    a[mi], b[ni], acc[mi][ni], 0, 0, 0);
    }

#pragma unroll
    for (int mi = 0; mi < 4; mi++)
#pragma unroll
        for (int ni = 0; ni < 4; ni++) {
            int n = n0 + wc * 64 + ni * 16 + fr;
            int h = n >> 6, d = n & 63;
            float bv_ = bias[n];
            int m_base = m0 + wr * 64 + mi * 16 + fg * 4;
            int b_ = m_base / TT, t0 = m_base % TT;
            if (z == 2) {
                size_t off = ((size_t)(b_ * NH + h) * HD + d) * (size_t)TT + t0;
                ushort4 o = { f2bf(acc[mi][ni][0] + bv_), f2bf(acc[mi][ni][1] + bv_),
                              f2bf(acc[mi][ni][2] + bv_), f2bf(acc[mi][ni][3] + bv_) };
                *reinterpret_cast<ushort4*>(&out[off]) = o;
            } else {
#pragma unroll
                for (int r = 0; r < 4; r++) {
                    size_t off = ((size_t)(b_ * NH + h) * TT + t0 + r) * (size_t)HD + d;
                    out[off] = f2bf((acc[mi][ni][r] + bv_) * scale);
                }
            }
        }
}

// ---------------------------------------------------------------------------
// Output projection GEMM: A and B staged via global_load_lds width-16.
// XCD swizzle: 36 consecutive decoded blocks per XCD. fp32 out [M,C] = d_out.
// ---------------------------------------------------------------------------
__global__ __launch_bounds__(256) void gemm_proj(
    const unsigned short* __restrict__ yb,
    const unsigned short* __restrict__ wp, const float* __restrict__ bp,
    float* __restrict__ out) {
    __shared__ unsigned short As[128][32];
    __shared__ unsigned short Bs[128][32];

    const int wg = (blockIdx.x & 7) * 36 + (blockIdx.x >> 3);  // nwg=288
    const int m0 = (wg / 6) * 128;
    const int n0 = (wg % 6) * 128;

    const int tid = threadIdx.x;
    const int lane = tid & 63;
    const int w = tid >> 6;
    const int wr = w >> 1, wc = w & 1;
    const int fr = lane & 15, fg = lane >> 4;

    const int br = tid >> 2, bc = (tid & 3) * 8;
    unsigned short* as0 = &As[0][0];
    unsigned short* bs0 = &Bs[0][0];

    f32x4 acc[4][4];
#pragma unroll
    for (int i = 0; i < 4; i++)
#pragma unroll
        for (int j = 0; j < 4; j++) acc[i][j] = (f32x4){0.f, 0.f, 0.f, 0.f};

    for (int k0 = 0; k0 < CC; k0 += 32) {
        __syncthreads();
#pragma unroll
        for (int i = 0; i < 2; i++) {
            gl_lds16(&yb[(size_t)(m0 + i * 64 + br) * CC + k0 + bc],
                     as0 + w * 512 + i * 2048);
            gl_lds16(&wp[(size_t)(n0 + i * 64 + br) * CC + k0 + bc],
                     bs0 + w * 512 + i * 2048);
        }
        __syncthreads();
        bf16x8 a[4], b[4];
#pragma unroll
        for (int mi = 0; mi < 4; mi++)
            a[mi] = *reinterpret_cast<const bf16x8*>(&As[wr * 64 + mi * 16 + fr][fg * 8]);
#pragma unroll
        for (int ni = 0; ni < 4; ni++)
            b[ni] = *reinterpret_cast<const bf16x8*>(&Bs[wc * 64 + ni * 16 + fr][fg * 8]);
#pragma unroll
        for (int mi = 0; mi < 4; mi++)
#pragma unroll
            for (int ni = 0; ni < 4; ni++)
                acc[mi][ni] = __builtin_amdgcn_mfma_f32_16x16x32_bf16(
                    a[mi], b[ni], acc[mi][ni], 0, 0, 0);
    }

#pragma unroll
    for (int mi = 0; mi < 4; mi++)
#pragma unroll
        for (int ni = 0; ni < 4; ni++) {
            int n = n0 + wc * 64 + ni * 16 + fr;
            float bv_ = bp[n];
#pragma unroll
            for (int r = 0; r < 4; r++) {
                int m = m0 + wr * 64 + mi * 16 + fg * 4 + r;
                out[(size_t)m * CC + n] = acc[mi][ni][r] + bv_;
            }
        }
}

// ---------------------------------------------------------------------------
// Flash attention (R7-proven, unchanged):
//  - fixed-shift softmax p=exp(S-10), row-sum via ones-MFMA (no cross-lane ops)
//  - KCHUNK=32, double-buffered K/V^T LDS (1 barrier/chunk), ~25 KB LDS
//  - XOR-swizzled Ps (zero write conflicts)
//  - grid: slot=gid&7 -> 6 (b,h) per XCD slot (K/V L2-resident), heavy-first
// Mask: valid iff (j%512) <= (i%512); q pre-scaled by 1/sqrt(D).
// ---------------------------------------------------------------------------
__global__ __launch_bounds__(256) void attn(
    const unsigned short* __restrict__ q, const unsigned short* __restrict__ k,
    const unsigned short* __restrict__ vt, unsigned short* __restrict__ y) {
    __shared__ unsigned short Ks[2][32][72];
    __shared__ unsigned short Vs[2][64][40];
    __shared__ unsigned short Ps[4][16][40];

    const int gid = blockIdx.x;
    const int slot = gid & 7;
    const int sub = (gid >> 3) % 6;
    const int bh = slot * 6 + sub;              // 6 bh per XCD slot
    const int qt = gid / 48;                    // 0..23, heavy-first
    const int qseg = 7 - qt / 3;                // 7..0
    const int sg0 = qt % 3;
    const int q0 = sg0 * 512 + qseg * 64;

    const int tid = threadIdx.x;
    const int w = tid >> 6;
    const int lane = tid & 63;
    const int fr = lane & 15, fg = lane >> 4;

    const size_t base = (size_t)bh * TT * HD;

    bf16x8 aq[2];
#pragma unroll
    for (int s = 0; s < 2; s++)
        aq[s] = *reinterpret_cast<const bf16x8*>(
            &q[base + (size_t)(q0 + w * 16 + fr) * HD + s * 32 + fg * 8]);

    f32x4 acc_o[4];
#pragma unroll
    for (int i = 0; i < 4; i++) acc_o[i] = (f32x4){0.f, 0.f, 0.f, 0.f};
    f32x4 acc_l = (f32x4){0.f, 0.f, 0.f, 0.f};

    const bf16x8 ones8 = {(short)0x3F80, (short)0x3F80, (short)0x3F80, (short)0x3F80,
                          (short)0x3F80, (short)0x3F80, (short)0x3F80, (short)0x3F80};

    const int kr = tid >> 3, kc = tid & 7;
    const int vr = tid >> 2, vc = tid & 3;

    uint4 kreg, vreg;
    auto issue = [&](int k0n) {
        kreg = *reinterpret_cast<const uint4*>(&k[base + (size_t)(k0n + kr) * HD + kc * 8]);
        vreg = *reinterpret_cast<const uint4*>(&vt[base + (size_t)vr * TT + k0n + vc * 8]);
    };
    auto wlds = [&](int b) {
        *reinterpret_cast<uint4*>(&Ks[b][kr][kc * 8]) = kreg;
        *reinterpret_cast<uint4*>(&Vs[b][vr][vc * 8]) = vreg;
    };

    const int per = 2 * qseg + 2;     // 32-key chunks per 512-segment
    const int ntot = 3 * per;

    issue(0);
    wlds(0);
    int cur = 0;
    int j = 0;
    int ji = 0, si = 0;

    for (int ci = 0; ci < ntot; ci++) {
        if (ci + 1 < ntot) {
            ji++; if (ji == per) { ji = 0; si++; }
            issue(si * 512 + ji * 32);
        }
        __syncthreads();

        f32x4 S[2];
#pragma unroll
        for (int nb = 0; nb < 2; nb++) {
            f32x4 sa = (f32x4){0.f, 0.f, 0.f, 0.f};
#pragma unroll
            for (int s = 0; s < 2; s++) {
                bf16x8 bk_ = *reinterpret_cast<const bf16x8*>(
                    &Ks[cur][nb * 16 + fr][s * 32 + fg * 8]);
                sa = __builtin_amdgcn_mfma_f32_16x16x32_bf16(aq[s], bk_, sa, 0, 0, 0);
            }
            S[nb] = sa;
        }

        if (j >= 2 * qseg) {
            const int joff = (j - 2 * qseg) * 32;
#pragma unroll
            for (int nb = 0; nb < 2; nb++)
#pragma unroll
                for (int r = 0; r < 4; r++) {
                    int ib = w * 16 + fg * 4 + r;
                    int jb = joff + nb * 16 + fr;
                    if (jb > ib) S[nb][r] = -1e30f;
                }
        }

#pragma unroll
        for (int nb = 0; nb < 2; nb++)
#pragma unroll
            for (int r = 0; r < 4; r++)
                Ps[w][fg * 4 + r][((nb ^ (fg >> 1)) * 16) + fr] =
                    f2bf(__expf(S[nb][r] - 10.f));

        bf16x8 ap = *reinterpret_cast<const bf16x8*>(
            &Ps[w][fr][(fg ^ (2 * (fr >> 3))) * 8]);
#pragma unroll
        for (int nd = 0; nd < 4; nd++) {
            bf16x8 bv_ = *reinterpret_cast<const bf16x8*>(&Vs[cur][nd * 16 + fr][fg * 8]);
            acc_o[nd] = __builtin_amdgcn_mfma_f32_16x16x32_bf16(ap, bv_, acc_o[nd], 0, 0, 0);
        }
        acc_l = __builtin_amdgcn_mfma_f32_16x16x32_bf16(ap, ones8, acc_l, 0, 0, 0);

        if (ci + 1 < ntot) wlds(cur ^ 1);
        cur ^= 1;
        if (++j == per) j = 0;
    }

    const int b_ = bh / NH, h = bh % NH;
#pragma unroll
    for (int r = 0; r < 4; r++) {
        float inv = 1.f / acc_l[r];
        int t = q0 + w * 16 + fg * 4 + r;
        size_t off = ((size_t)b_ * TT + t) * CC + h * HD;
#pragma unroll
        for (int nd = 0; nd < 4; nd++)
            y[off + nd * 16 + fr] = f2bf(acc_o[nd][r] * inv);
    }
}

extern "C" void kernel_launch(void* const* d_in, const int* in_sizes, int n_in,
                              void* d_out, int out_size, void* d_ws, size_t ws_size,
                              hipStream_t stream) {
    const float* x  = (const float*)d_in[0];
    const float* Wq = (const float*)d_in[1];
    const float* bq = (const float*)d_in[2];
    const float* Wk = (const float*)d_in[3];
    const float* bk = (const float*)d_in[4];
    const float* Wv = (const float*)d_in[5];
    const float* bv = (const float*)d_in[6];
    const float* Wp = (const float*)d_in[7];
    const float* bp = (const float*)d_in[8];
    float* out = (float*)d_out;

    unsigned short* ws  = (unsigned short*)d_ws;
    unsigned short* wqb = ws;                              // CC*CC each
    unsigned short* wkb = wqb + (size_t)CC * CC;
    unsigned short* wvb = wkb + (size_t)CC * CC;
    unsigned short* wpb = wvb + (size_t)CC * CC;
    unsigned short* xb  = wpb + (size_t)CC * CC;           // MM*CC each
    unsigned short* qb_ = xb  + (size_t)MM * CC;
    unsigned short* kb_ = qb_ + (size_t)MM * CC;
    unsigned short* vt_ = kb_ + (size_t)MM * CC;           // [B,H,D,T]
    unsigned short* yb  = vt_ + (size_t)MM * CC;

    const int n4w = CC * CC / 4;
    const int n4x = MM * CC / 4;
    convert_w4<<<dim3((n4w + 255) / 256, 4), 256, 0, stream>>>(
        Wq, Wk, Wv, Wp, wqb, wkb, wvb, wpb, n4w);
    convert_x<<<(n4x + 255) / 256, 256, 0, stream>>>(x, xb, n4x);

    gemm_qkv<<<dim3(864), 256, 0, stream>>>(
        xb, wqb, bq, wkb, bk, wvb, bv, qb_, kb_, vt_);
    attn<<<dim3(48 * 24), 256, 0, stream>>>(qb_, kb_, vt_, yb);
    gemm_proj<<<dim3(288), 256, 0, stream>>>(yb, wpb, bp, out);
}